// Round 6
// baseline (468.127 us; speedup 1.0000x reference)
//
#include <hip/hip_runtime.h>
#include <hip/hip_bf16.h>

#define D_MODEL 1024
#define NHEADS  16
#define HD      64
#define BATCH   2
#define SEQ     2048
#define MROWS   4096
#define NQKV    1152    // 1024 Q | 64 K | 64 V
#define NSPLIT  4

typedef short  short8  __attribute__((ext_vector_type(8)));
typedef float  floatx4 __attribute__((ext_vector_type(4)));

// fp32 -> bf16 (RNE)
__device__ inline short f2bf(float f) {
  unsigned u = __builtin_bit_cast(unsigned, f);
  u = (u + 0x7FFF + ((u >> 16) & 1)) >> 16;
  return (short)u;
}

// pack two f32 -> dword of two bf16 (truncation) in ONE v_perm_b32
__device__ inline unsigned pack_trunc(float lo, float hi) {
  return __builtin_amdgcn_perm(__builtin_bit_cast(unsigned, hi),
                               __builtin_bit_cast(unsigned, lo), 0x07060302u);
}

// async 16B global -> LDS (lds base wave-uniform; HW adds lane*16)
__device__ inline void async_copy16(const short* g, short* l) {
  __builtin_amdgcn_global_load_lds(
      (const __attribute__((address_space(1))) unsigned int*)g,
      (__attribute__((address_space(3))) unsigned int*)l, 16, 0, 0);
}

// ---------------------------------------------------------------------------
// Mega prep: weight transposes (bf16 B^T pack), bias pack, x -> bf16
// ---------------------------------------------------------------------------
__global__ __launch_bounds__(256)
void prep_kernel(const float* __restrict__ x,  const float* __restrict__ Wq,
                 const float* __restrict__ Wk, const float* __restrict__ Wv,
                 const float* __restrict__ Wo, const float* __restrict__ bq,
                 const float* __restrict__ bk, const float* __restrict__ bv,
                 short* __restrict__ xb, short* __restrict__ Wqkv_t,
                 short* __restrict__ Wo_t, float* __restrict__ bqkv) {
  const int id = blockIdx.x;
  const int t  = threadIdx.x;
  if (id < 544) {
    __shared__ short Ts[64 * 72];
    const float* src; short* dst; int N, off, tile;
    if (id < 256)      { src = Wq; dst = Wqkv_t; N = 1024; off = 0;    tile = id; }
    else if (id < 272) { src = Wk; dst = Wqkv_t; N = 64;   off = 1024; tile = id - 256; }
    else if (id < 288) { src = Wv; dst = Wqkv_t; N = 64;   off = 1088; tile = id - 272; }
    else               { src = Wo; dst = Wo_t;   N = 1024; off = 0;    tile = id - 288; }
    const int k0 = (N == 1024) ? (tile & 15) * 64 : tile * 64;
    const int n0 = (N == 1024) ? (tile >> 4) * 64 : 0;
    {
      const int r = t >> 2, c = (t & 3) * 16;
      const float* s = src + (size_t)(k0 + r) * N + n0 + c;
#pragma unroll
      for (int j = 0; j < 16; j += 4) {
        float4 v = *reinterpret_cast<const float4*>(s + j);
        Ts[r * 72 + c + j + 0] = f2bf(v.x); Ts[r * 72 + c + j + 1] = f2bf(v.y);
        Ts[r * 72 + c + j + 2] = f2bf(v.z); Ts[r * 72 + c + j + 3] = f2bf(v.w);
      }
    }
    __syncthreads();
    {
      const int n = t >> 2, kc = (t & 3) * 16;
      short8 o0, o1;
#pragma unroll
      for (int j = 0; j < 8; ++j) o0[j] = Ts[(kc + j) * 72 + n];
#pragma unroll
      for (int j = 0; j < 8; ++j) o1[j] = Ts[(kc + 8 + j) * 72 + n];
      short* d = dst + (size_t)(off + n0 + n) * 1024 + k0 + kc;
      *reinterpret_cast<short8*>(d)     = o0;
      *reinterpret_cast<short8*>(d + 8) = o1;
    }
  } else if (id < 549) {
    const int i = (id - 544) * 256 + t;
    if (i < 1024)      bqkv[i] = bq[i];
    else if (i < 1088) bqkv[i] = bk[i - 1024];
    else if (i < 1152) bqkv[i] = bv[i - 1088];
  } else {
    const int i = ((id - 549) * 256 + t) * 8;
    if (i < MROWS * D_MODEL) {
      float4 a = *reinterpret_cast<const float4*>(x + i);
      float4 b = *reinterpret_cast<const float4*>(x + i + 4);
      short8 o;
      o[0] = f2bf(a.x); o[1] = f2bf(a.y); o[2] = f2bf(a.z); o[3] = f2bf(a.w);
      o[4] = f2bf(b.x); o[5] = f2bf(b.y); o[6] = f2bf(b.z); o[7] = f2bf(b.w);
      *reinterpret_cast<short8*>(xb + i) = o;
    }
  }
}

// ---------------------------------------------------------------------------
// V^T pre-pass: QKV cols 1088..1151 -> Vtg[b][d][s]  ([2][64][2048] bf16)
// ---------------------------------------------------------------------------
__global__ __launch_bounds__(256)
void vt_kernel(const short* __restrict__ QKV, short* __restrict__ Vtg) {
  __shared__ short Ts[64 * 72];
  const int b = blockIdx.y, k0 = blockIdx.x * 64;
  const int t = threadIdx.x;
  {
    const int r = t >> 2, c = (t & 3) * 16;
    const short* s = &QKV[(size_t)(b * SEQ + k0 + r) * NQKV + 1088 + c];
    *reinterpret_cast<short8*>(&Ts[r * 72 + c])     = *reinterpret_cast<const short8*>(s);
    *reinterpret_cast<short8*>(&Ts[r * 72 + c + 8]) = *reinterpret_cast<const short8*>(s + 8);
  }
  __syncthreads();
  {
    const int d = t >> 2, kc = (t & 3) * 16;
    short8 o0, o1;
#pragma unroll
    for (int j = 0; j < 8; ++j) o0[j] = Ts[(kc + j) * 72 + d];
#pragma unroll
    for (int j = 0; j < 8; ++j) o1[j] = Ts[(kc + 8 + j) * 72 + d];
    short* dst = &Vtg[(size_t)(b * 64 + d) * SEQ + k0 + kc];
    *reinterpret_cast<short8*>(dst)     = o0;
    *reinterpret_cast<short8*>(dst + 8) = o1;
  }
}

// ---------------------------------------------------------------------------
// bf16 MFMA GEMM, 128x64 tile, BK=64 (half the barriers of BK=32).
// C[M,N] = A[M,K] @ Bt[N,K]^T + bias[N].  4 waves as 2x2 over (64,32).
// LDS XOR swizzle: rows of 64 shorts (8 chunks); chunk c of row r stored at
// c^(r&7).  Both DMA staging and ds_read_b128 frag reads conflict-free.
// ---------------------------------------------------------------------------
template<bool OUT_BF16>
__global__ __launch_bounds__(256)
void gemm_mfma_bt(const short* __restrict__ A, const short* __restrict__ Bt,
                  const float* __restrict__ bias, void* __restrict__ Cout,
                  int M, int N, int K) {
  __shared__ short As[128 * 64];   // 16 KB
  __shared__ short Bs[64 * 64];    // 8 KB
  const int t    = threadIdx.x;
  const int w    = t >> 6;
  const int lane = t & 63;
  const int quad = lane >> 4;
  const int l16  = lane & 15;
  const int bm   = blockIdx.x * 128;
  const int bn   = blockIdx.y * 64;
  const int wm   = (w >> 1) * 64;
  const int wn   = (w & 1) * 32;

  // staging slot s (16B): row = s>>3, phys chunk = s&7, logical = (s&7)^(row&7)
  const int srow = t >> 3;                        // issue 0 rows 0..31 (A), +32,+64,+96
  const int cc   = ((t & 7) ^ (srow & 7)) * 8;
  const short* gA = A  + (size_t)(bm + srow) * K + cc;
  const short* gB = Bt + (size_t)(bn + srow) * K + cc;
  short* lA = As + t * 8;         // slot s = i*256 + t -> LDS offset s*8 shorts
  short* lB = Bs + t * 8;

  floatx4 acc[4][2];
#pragma unroll
  for (int i = 0; i < 4; ++i)
#pragma unroll
    for (int j = 0; j < 2; ++j) acc[i][j] = (floatx4){0.f, 0.f, 0.f, 0.f};

  const int xr = l16 & 7;

  for (int k0 = 0; k0 < K; k0 += 64) {
    __syncthreads();
    async_copy16(gA + k0, lA);
    async_copy16(gA + (size_t)32 * K + k0, lA + 2048);
    async_copy16(gA + (size_t)64 * K + k0, lA + 4096);
    async_copy16(gA + (size_t)96 * K + k0, lA + 6144);
    async_copy16(gB + k0, lB);
    async_copy16(gB + (size_t)32 * K + k0, lB + 2048);
    __syncthreads();

    short8 fa0[4], fa1[4], fb0[2], fb1[2];
#pragma unroll
    for (int mi = 0; mi < 4; ++mi) {
      const int row = wm + mi * 16 + l16;
      fa0[mi] = *reinterpret_cast<const short8*>(&As[row * 64 + (quad ^ xr) * 8]);
      fa1[mi] = *reinterpret_cast<const short8*>(&As[row * 64 + ((4 + quad) ^ xr) * 8]);
    }
#pragma unroll
    for (int ni = 0; ni < 2; ++ni) {
      const int row = wn + ni * 16 + l16;
      fb0[ni] = *reinterpret_cast<const short8*>(&Bs[row * 64 + (quad ^ xr) * 8]);
      fb1[ni] = *reinterpret_cast<const short8*>(&Bs[row * 64 + ((4 + quad) ^ xr) * 8]);
    }
#pragma unroll
    for (int mi = 0; mi < 4; ++mi)
#pragma unroll
      for (int ni = 0; ni < 2; ++ni) {
        acc[mi][ni] = __builtin_amdgcn_mfma_f32_16x16x32_bf16(fa0[mi], fb0[ni], acc[mi][ni], 0, 0, 0);
        acc[mi][ni] = __builtin_amdgcn_mfma_f32_16x16x32_bf16(fa1[mi], fb1[ni], acc[mi][ni], 0, 0, 0);
      }
  }

#pragma unroll
  for (int ni = 0; ni < 2; ++ni) {
    const int col = bn + wn + ni * 16 + l16;
    const float bs = bias[col];
#pragma unroll
    for (int mi = 0; mi < 4; ++mi) {
      const int row = bm + wm + mi * 16 + quad * 4;
#pragma unroll
      for (int r = 0; r < 4; ++r) {
        const float v = acc[mi][ni][r] + bs;
        if (OUT_BF16)
          ((short*)Cout)[(size_t)(row + r) * N + col] = f2bf(v);
        else
          ((float*)Cout)[(size_t)(row + r) * N + col] = v;
      }
    }
  }
}

// ---------------------------------------------------------------------------
// bf16 flash MQA: 512 threads (8 waves), 2 heads/block (shared K/V staging),
// KV-split=4.  Waves: head = w>>2, wl = w&3; wave owns 32 q-rows (2 strips,
// processed sequentially, sharing a 16-row wave-private Ps region).
// No-max softmax: p = exp2(s * 0.125*log2e)  (scores bounded, exact combine).
// Partials: O fp16, l fp32.
// ---------------------------------------------------------------------------
__global__ __launch_bounds__(512, 8)
void mqa_flash_bf16(const short* __restrict__ QKV, const short* __restrict__ Vtg,
                    _Float16* __restrict__ Opart, float* __restrict__ lpart) {
  const int pr    = blockIdx.y;          // bh-pair 0..15
  const int b     = pr >> 3;
  const int h0    = (pr & 7) * 2;
  const int s0    = blockIdx.x * 128;
  const int split = blockIdx.z;
  const int t     = threadIdx.x;
  const int w     = t >> 6;              // 0..7
  const int wl    = w & 3;
  const int h     = h0 + (w >> 2);
  const int bh    = b * 16 + h;
  const int lane  = t & 63;
  const int quad  = lane >> 4;
  const int l16   = lane & 15;

  __shared__ short KVs[8192];            // Ks [0,4096), Vt [4096,8192)
  __shared__ short Ps[8 * 16 * 72];      // 16 rows per wave, stride 72
  short* Ks = KVs;
  short* Vt = KVs + 4096;
  short* myPs = Ps + w * 16 * 72;

  // Q B-frags for both strips
  short8 aq[2][2];
#pragma unroll
  for (int st = 0; st < 2; ++st) {
    const short* qrow = &QKV[(size_t)(b * SEQ + s0 + wl * 32 + st * 16 + l16) * NQKV + h * HD];
    aq[st][0] = *reinterpret_cast<const short8*>(qrow + quad * 8);
    aq[st][1] = *reinterpret_cast<const short8*>(qrow + 32 + quad * 8);
  }

  floatx4 oacc[2][4];
  floatx4 lacc[2];
#pragma unroll
  for (int st = 0; st < 2; ++st) {
    lacc[st] = (floatx4){0.f, 0.f, 0.f, 0.f};
#pragma unroll
    for (int dg = 0; dg < 4; ++dg) oacc[st][dg] = (floatx4){0.f, 0.f, 0.f, 0.f};
  }

  short8 ones;
#pragma unroll
  for (int j = 0; j < 8; ++j) ones[j] = (short)0x3F80;

  // staging: 512 lanes, one call per buffer. slot s = t: row = s>>3, chunk
  // phys = s&7, logical = (s&7)^(row&7).  Wave-uniform LDS base + lane*16.
  const int srow = t >> 3;               // 0..63
  const int cc   = ((t & 7) ^ (srow & 7)) * 8;
  const short* gK = QKV + (size_t)(b * SEQ + srow) * NQKV + 1024 + cc;
  const short* gV = Vtg + (size_t)(b * 64 + srow) * SEQ + cc;
  short* lK = Ks + w * 512;
  short* lV = Vt + w * 512;

  const int xr = l16 & 7;
  const float C1 = 0.18033688f;          // 0.125 * log2(e)
  const int kbase = split * (SEQ / NSPLIT);

  for (int kk = kbase; kk < kbase + SEQ / NSPLIT; kk += 64) {
    __syncthreads();
    async_copy16(gK + (size_t)kk * NQKV, lK);
    async_copy16(gV + kk, lV);
    __syncthreads();

    // K A-frags + V B-frags (shared across strips)
    short8 kb[4][2], vb[4][2];
#pragma unroll
    for (int kg = 0; kg < 4; ++kg) {
      kb[kg][0] = *reinterpret_cast<const short8*>(&Ks[(kg * 16 + l16) * 64 + (quad ^ xr) * 8]);
      kb[kg][1] = *reinterpret_cast<const short8*>(&Ks[(kg * 16 + l16) * 64 + ((4 + quad) ^ xr) * 8]);
    }
#pragma unroll
    for (int dg = 0; dg < 4; ++dg) {
      vb[dg][0] = *reinterpret_cast<const short8*>(&Vt[(dg * 16 + l16) * 64 + (quad ^ xr) * 8]);
      vb[dg][1] = *reinterpret_cast<const short8*>(&Vt[(dg * 16 + l16) * 64 + ((4 + quad) ^ xr) * 8]);
    }

#pragma unroll
    for (int st = 0; st < 2; ++st) {
      // S^T = K·Q^T ; p = exp2(s*C1); pack (v_perm trunc) -> wave-private Ps
#pragma unroll
      for (int kg = 0; kg < 4; ++kg) {
        floatx4 s4 = (floatx4){0.f, 0.f, 0.f, 0.f};
        s4 = __builtin_amdgcn_mfma_f32_16x16x32_bf16(kb[kg][0], aq[st][0], s4, 0, 0, 0);
        s4 = __builtin_amdgcn_mfma_f32_16x16x32_bf16(kb[kg][1], aq[st][1], s4, 0, 0, 0);
        float p0 = __builtin_exp2f(s4[0] * C1);
        float p1 = __builtin_exp2f(s4[1] * C1);
        float p2 = __builtin_exp2f(s4[2] * C1);
        float p3 = __builtin_exp2f(s4[3] * C1);
        uint2 pk;
        pk.x = pack_trunc(p0, p1);
        pk.y = pack_trunc(p2, p3);
        *reinterpret_cast<uint2*>(&myPs[l16 * 72 + kg * 16 + quad * 4]) = pk;
      }
      // O += P·V ; l += P·ones   (wave-private: in-order LDS, no barrier)
      short8 ap0 = *reinterpret_cast<const short8*>(&myPs[l16 * 72 + quad * 8]);
      short8 ap1 = *reinterpret_cast<const short8*>(&myPs[l16 * 72 + 32 + quad * 8]);
      lacc[st] = __builtin_amdgcn_mfma_f32_16x16x32_bf16(ap0, ones, lacc[st], 0, 0, 0);
      lacc[st] = __builtin_amdgcn_mfma_f32_16x16x32_bf16(ap1, ones, lacc[st], 0, 0, 0);
#pragma unroll
      for (int dg = 0; dg < 4; ++dg) {
        oacc[st][dg] = __builtin_amdgcn_mfma_f32_16x16x32_bf16(ap0, vb[dg][0], oacc[st][dg], 0, 0, 0);
        oacc[st][dg] = __builtin_amdgcn_mfma_f32_16x16x32_bf16(ap1, vb[dg][1], oacc[st][dg], 0, 0, 0);
      }
    }
  }

  // partial epilogue: fp16 O, fp32 l
#pragma unroll
  for (int st = 0; st < 2; ++st) {
#pragma unroll
    for (int rg = 0; rg < 4; ++rg) {
      const int qg = s0 + wl * 32 + st * 16 + quad * 4 + rg;
      _Float16* dst = Opart + ((size_t)(split * 32 + bh) * SEQ + qg) * 64 + l16;
#pragma unroll
      for (int dg = 0; dg < 4; ++dg) dst[dg * 16] = (_Float16)oacc[st][dg][rg];
      if (l16 == 0) lpart[(size_t)(split * 32 + bh) * SEQ + qg] = lacc[st][rg];
    }
  }
}

// ---------------------------------------------------------------------------
// combine: Att[b*S+q][h*64+d] = (sum_s O_s)/(sum_s l_s), bf16 out
// ---------------------------------------------------------------------------
__global__ __launch_bounds__(256)
void combine_kernel(const _Float16* __restrict__ Opart, const float* __restrict__ lpart,
                    short* __restrict__ Att) {
  const int idx = blockIdx.x * 256 + threadIdx.x;   // 524288 total
  const int r   = idx >> 3;                          // bh*2048 + q
  const int d0  = (idx & 7) * 8;
  float l = 0.f;
  float o[8] = {0.f,0.f,0.f,0.f,0.f,0.f,0.f,0.f};
#pragma unroll
  for (int s = 0; s < NSPLIT; ++s) {
    const _Float16* op = Opart + ((size_t)(s * 32 * SEQ) + r) * 64 + d0;
    l += lpart[(size_t)s * 32 * SEQ + r];
#pragma unroll
    for (int j = 0; j < 8; ++j) o[j] += (float)op[j];
  }
  const float inv = 1.0f / l;
  short8 ov;
#pragma unroll
  for (int j = 0; j < 8; ++j) ov[j] = f2bf(o[j] * inv);
  const int bhh = r >> 11, q = r & 2047;
  const int bb = bhh >> 4, hh = bhh & 15;
  *reinterpret_cast<short8*>(&Att[(size_t)(bb * SEQ + q) * D_MODEL + hh * HD + d0]) = ov;
}

// ---------------------------------------------------------------------------
extern "C" void kernel_launch(void* const* d_in, const int* in_sizes, int n_in,
                              void* d_out, int out_size, void* d_ws, size_t ws_size,
                              hipStream_t stream) {
  const float* x  = (const float*)d_in[0];
  const float* Wq = (const float*)d_in[1];
  const float* bq = (const float*)d_in[2];
  const float* Wk = (const float*)d_in[3];
  const float* bk = (const float*)d_in[4];
  const float* Wv = (const float*)d_in[5];
  const float* bv = (const float*)d_in[6];
  const float* Wo = (const float*)d_in[7];
  const float* bo = (const float*)d_in[8];
  float* out = (float*)d_out;

  short* Wqkv_t = (short*)d_ws;                              // 1152*1024
  short* Wo_t   = Wqkv_t + (size_t)NQKV * D_MODEL;           // 1024*1024
  short* xb     = Wo_t + (size_t)D_MODEL * D_MODEL;          // 4096*1024
  short* QKV    = xb + (size_t)MROWS * D_MODEL;              // 4096*1152
  short* Att    = QKV + (size_t)MROWS * NQKV;                // 4096*1024
  short* Vtg    = Att + (size_t)MROWS * D_MODEL;             // 2*64*2048
  float* bqkv   = (float*)(Vtg + (size_t)BATCH * HD * SEQ);  // 1152
  float* lpart  = bqkv + 1152;                               // 4*32*2048
  _Float16* Opart = (_Float16*)(lpart + (size_t)NSPLIT * 32 * SEQ);  // 4*32*2048*64

  prep_kernel<<<2597, 256, 0, stream>>>(x, Wq, Wk, Wv, Wo, bq, bk, bv,
                                        xb, Wqkv_t, Wo_t, bqkv);

  gemm_mfma_bt<true><<<dim3(MROWS / 128, NQKV / 64), 256, 0, stream>>>(
      xb, Wqkv_t, bqkv, QKV, MROWS, NQKV, D_MODEL);

  vt_kernel<<<dim3(SEQ / 64, BATCH), 256, 0, stream>>>(QKV, Vtg);

  mqa_flash_bf16<<<dim3(SEQ / 128, NHEADS, NSPLIT), 512, 0, stream>>>(
      QKV, Vtg, Opart, lpart);

  combine_kernel<<<2048, 256, 0, stream>>>(Opart, lpart, Att);

  gemm_mfma_bt<false><<<dim3(MROWS / 128, D_MODEL / 64), 256, 0, stream>>>(
      Att, Wo_t, bo, out, MROWS, D_MODEL, D_MODEL);
}

// Round 7
// 248.002 us; speedup vs baseline: 1.8876x; 1.8876x over previous
//
#include <hip/hip_runtime.h>
#include <hip/hip_bf16.h>

#define D_MODEL 1024
#define NHEADS  16
#define HD      64
#define BATCH   2
#define SEQ     2048
#define MROWS   4096
#define NQKV    1152    // 1024 Q | 64 K | 64 V
#define NSPLIT  2

typedef short  short8  __attribute__((ext_vector_type(8)));
typedef float  floatx4 __attribute__((ext_vector_type(4)));

// fp32 -> bf16 (RNE)
__device__ inline short f2bf(float f) {
  unsigned u = __builtin_bit_cast(unsigned, f);
  u = (u + 0x7FFF + ((u >> 16) & 1)) >> 16;
  return (short)u;
}

// pack two f32 -> dword of two bf16 (truncation) in ONE v_perm_b32
__device__ inline unsigned pack_trunc(float lo, float hi) {
  return __builtin_amdgcn_perm(__builtin_bit_cast(unsigned, hi),
                               __builtin_bit_cast(unsigned, lo), 0x07060302u);
}

// async 16B global -> LDS (lds base wave-uniform; HW adds lane*16)
__device__ inline void async_copy16(const short* g, short* l) {
  __builtin_amdgcn_global_load_lds(
      (const __attribute__((address_space(1))) unsigned int*)g,
      (__attribute__((address_space(3))) unsigned int*)l, 16, 0, 0);
}

// ---------------------------------------------------------------------------
// Mega prep: weight transposes (bf16 B^T pack), bias pack, x -> bf16
// ---------------------------------------------------------------------------
__global__ __launch_bounds__(256)
void prep_kernel(const float* __restrict__ x,  const float* __restrict__ Wq,
                 const float* __restrict__ Wk, const float* __restrict__ Wv,
                 const float* __restrict__ Wo, const float* __restrict__ bq,
                 const float* __restrict__ bk, const float* __restrict__ bv,
                 short* __restrict__ xb, short* __restrict__ Wqkv_t,
                 short* __restrict__ Wo_t, float* __restrict__ bqkv) {
  const int id = blockIdx.x;
  const int t  = threadIdx.x;
  if (id < 544) {
    __shared__ short Ts[64 * 72];
    const float* src; short* dst; int N, off, tile;
    if (id < 256)      { src = Wq; dst = Wqkv_t; N = 1024; off = 0;    tile = id; }
    else if (id < 272) { src = Wk; dst = Wqkv_t; N = 64;   off = 1024; tile = id - 256; }
    else if (id < 288) { src = Wv; dst = Wqkv_t; N = 64;   off = 1088; tile = id - 272; }
    else               { src = Wo; dst = Wo_t;   N = 1024; off = 0;    tile = id - 288; }
    const int k0 = (N == 1024) ? (tile & 15) * 64 : tile * 64;
    const int n0 = (N == 1024) ? (tile >> 4) * 64 : 0;
    {
      const int r = t >> 2, c = (t & 3) * 16;
      const float* s = src + (size_t)(k0 + r) * N + n0 + c;
#pragma unroll
      for (int j = 0; j < 16; j += 4) {
        float4 v = *reinterpret_cast<const float4*>(s + j);
        Ts[r * 72 + c + j + 0] = f2bf(v.x); Ts[r * 72 + c + j + 1] = f2bf(v.y);
        Ts[r * 72 + c + j + 2] = f2bf(v.z); Ts[r * 72 + c + j + 3] = f2bf(v.w);
      }
    }
    __syncthreads();
    {
      const int n = t >> 2, kc = (t & 3) * 16;
      short8 o0, o1;
#pragma unroll
      for (int j = 0; j < 8; ++j) o0[j] = Ts[(kc + j) * 72 + n];
#pragma unroll
      for (int j = 0; j < 8; ++j) o1[j] = Ts[(kc + 8 + j) * 72 + n];
      short* d = dst + (size_t)(off + n0 + n) * 1024 + k0 + kc;
      *reinterpret_cast<short8*>(d)     = o0;
      *reinterpret_cast<short8*>(d + 8) = o1;
    }
  } else if (id < 549) {
    const int i = (id - 544) * 256 + t;
    if (i < 1024)      bqkv[i] = bq[i];
    else if (i < 1088) bqkv[i] = bk[i - 1024];
    else if (i < 1152) bqkv[i] = bv[i - 1088];
  } else {
    const int i = ((id - 549) * 256 + t) * 8;
    if (i < MROWS * D_MODEL) {
      float4 a = *reinterpret_cast<const float4*>(x + i);
      float4 b = *reinterpret_cast<const float4*>(x + i + 4);
      short8 o;
      o[0] = f2bf(a.x); o[1] = f2bf(a.y); o[2] = f2bf(a.z); o[3] = f2bf(a.w);
      o[4] = f2bf(b.x); o[5] = f2bf(b.y); o[6] = f2bf(b.z); o[7] = f2bf(b.w);
      *reinterpret_cast<short8*>(xb + i) = o;
    }
  }
}

// ---------------------------------------------------------------------------
// V^T pre-pass: QKV cols 1088..1151 -> Vtg[b][d][s]  ([2][64][2048] bf16)
// ---------------------------------------------------------------------------
__global__ __launch_bounds__(256)
void vt_kernel(const short* __restrict__ QKV, short* __restrict__ Vtg) {
  __shared__ short Ts[64 * 72];
  const int b = blockIdx.y, k0 = blockIdx.x * 64;
  const int t = threadIdx.x;
  {
    const int r = t >> 2, c = (t & 3) * 16;
    const short* s = &QKV[(size_t)(b * SEQ + k0 + r) * NQKV + 1088 + c];
    *reinterpret_cast<short8*>(&Ts[r * 72 + c])     = *reinterpret_cast<const short8*>(s);
    *reinterpret_cast<short8*>(&Ts[r * 72 + c + 8]) = *reinterpret_cast<const short8*>(s + 8);
  }
  __syncthreads();
  {
    const int d = t >> 2, kc = (t & 3) * 16;
    short8 o0, o1;
#pragma unroll
    for (int j = 0; j < 8; ++j) o0[j] = Ts[(kc + j) * 72 + d];
#pragma unroll
    for (int j = 0; j < 8; ++j) o1[j] = Ts[(kc + 8 + j) * 72 + d];
    short* dst = &Vtg[(size_t)(b * 64 + d) * SEQ + k0 + kc];
    *reinterpret_cast<short8*>(dst)     = o0;
    *reinterpret_cast<short8*>(dst + 8) = o1;
  }
}

// ---------------------------------------------------------------------------
// bf16 MFMA GEMM, 128x64 tile, BK=64.  C = A @ Bt^T + bias.
// SCALE_N: columns < SCALE_N additionally scaled by 0.125*log2(e) (folds the
// attention 1/sqrt(hd) and exp->exp2 conversion into Q at zero cost).
// ---------------------------------------------------------------------------
template<bool OUT_BF16, int SCALE_N>
__global__ __launch_bounds__(256)
void gemm_mfma_bt(const short* __restrict__ A, const short* __restrict__ Bt,
                  const float* __restrict__ bias, void* __restrict__ Cout,
                  int M, int N, int K) {
  __shared__ short As[128 * 64];   // 16 KB
  __shared__ short Bs[64 * 64];    // 8 KB
  const int t    = threadIdx.x;
  const int w    = t >> 6;
  const int lane = t & 63;
  const int quad = lane >> 4;
  const int l16  = lane & 15;
  const int bm   = blockIdx.x * 128;
  const int bn   = blockIdx.y * 64;
  const int wm   = (w >> 1) * 64;
  const int wn   = (w & 1) * 32;

  const int srow = t >> 3;
  const int cc   = ((t & 7) ^ (srow & 7)) * 8;
  const short* gA = A  + (size_t)(bm + srow) * K + cc;
  const short* gB = Bt + (size_t)(bn + srow) * K + cc;
  short* lA = As + t * 8;
  short* lB = Bs + t * 8;

  floatx4 acc[4][2];
#pragma unroll
  for (int i = 0; i < 4; ++i)
#pragma unroll
    for (int j = 0; j < 2; ++j) acc[i][j] = (floatx4){0.f, 0.f, 0.f, 0.f};

  const int xr = l16 & 7;

  for (int k0 = 0; k0 < K; k0 += 64) {
    __syncthreads();
    async_copy16(gA + k0, lA);
    async_copy16(gA + (size_t)32 * K + k0, lA + 2048);
    async_copy16(gA + (size_t)64 * K + k0, lA + 4096);
    async_copy16(gA + (size_t)96 * K + k0, lA + 6144);
    async_copy16(gB + k0, lB);
    async_copy16(gB + (size_t)32 * K + k0, lB + 2048);
    __syncthreads();

    short8 fa0[4], fa1[4], fb0[2], fb1[2];
#pragma unroll
    for (int mi = 0; mi < 4; ++mi) {
      const int row = wm + mi * 16 + l16;
      fa0[mi] = *reinterpret_cast<const short8*>(&As[row * 64 + (quad ^ xr) * 8]);
      fa1[mi] = *reinterpret_cast<const short8*>(&As[row * 64 + ((4 + quad) ^ xr) * 8]);
    }
#pragma unroll
    for (int ni = 0; ni < 2; ++ni) {
      const int row = wn + ni * 16 + l16;
      fb0[ni] = *reinterpret_cast<const short8*>(&Bs[row * 64 + (quad ^ xr) * 8]);
      fb1[ni] = *reinterpret_cast<const short8*>(&Bs[row * 64 + ((4 + quad) ^ xr) * 8]);
    }
#pragma unroll
    for (int mi = 0; mi < 4; ++mi)
#pragma unroll
      for (int ni = 0; ni < 2; ++ni) {
        acc[mi][ni] = __builtin_amdgcn_mfma_f32_16x16x32_bf16(fa0[mi], fb0[ni], acc[mi][ni], 0, 0, 0);
        acc[mi][ni] = __builtin_amdgcn_mfma_f32_16x16x32_bf16(fa1[mi], fb1[ni], acc[mi][ni], 0, 0, 0);
      }
  }

#pragma unroll
  for (int ni = 0; ni < 2; ++ni) {
    const int col = bn + wn + ni * 16 + l16;
    const float bs = bias[col];
    const float sc = (col < SCALE_N) ? 0.18033688f : 1.0f;  // 0.125*log2(e)
#pragma unroll
    for (int mi = 0; mi < 4; ++mi) {
      const int row = bm + wm + mi * 16 + quad * 4;
#pragma unroll
      for (int r = 0; r < 4; ++r) {
        const float v = (acc[mi][ni][r] + bs) * sc;
        if (OUT_BF16)
          ((short*)Cout)[(size_t)(row + r) * N + col] = f2bf(v);
        else
          ((float*)Cout)[(size_t)(row + r) * N + col] = v;
      }
    }
  }
}

// ---------------------------------------------------------------------------
// Barrier-free bf16 flash MQA.
//   - K/V fragments loaded DIRECTLY from global (L1/L2-resident tiles):
//     no block-level staging, no __syncthreads anywhere.
//   - LDS holds only the wave-private 16-row P scratch (C->A layout xform).
//   - Q pre-scaled by 0.125*log2e in the QKV GEMM: p = exp2(s) directly.
//   - Wave owns 32 q-rows (2 sequential strips); KV-split via grid.z.
//   - Partials: O fp16, l fp32 (exact combine: exp-space is linear).
// ---------------------------------------------------------------------------
__global__ __launch_bounds__(256, 4)
void mqa_flash_bf16(const short* __restrict__ QKV, const short* __restrict__ Vtg,
                    _Float16* __restrict__ Opart, float* __restrict__ lpart) {
  const int bh    = blockIdx.y;
  const int b     = bh >> 4;
  const int h     = bh & 15;
  const int s0    = blockIdx.x * 128;
  const int split = blockIdx.z;
  const int t     = threadIdx.x;
  const int w     = t >> 6;
  const int lane  = t & 63;
  const int quad  = lane >> 4;
  const int l16   = lane & 15;

  __shared__ short Ps[4 * 16 * 72];   // 9.2 KB total, wave-private 16-row regions
  short* myPs = Ps + w * 16 * 72;

  // Q B-frags (pre-scaled in GEMM epilogue)
  short8 aq[2][2];
#pragma unroll
  for (int st = 0; st < 2; ++st) {
    const short* qrow = &QKV[(size_t)(b * SEQ + s0 + w * 32 + st * 16 + l16) * NQKV + h * HD];
    aq[st][0] = *reinterpret_cast<const short8*>(qrow + quad * 8);
    aq[st][1] = *reinterpret_cast<const short8*>(qrow + 32 + quad * 8);
  }

  floatx4 oacc[2][4];
  floatx4 lacc[2];
#pragma unroll
  for (int st = 0; st < 2; ++st) {
    lacc[st] = (floatx4){0.f, 0.f, 0.f, 0.f};
#pragma unroll
    for (int dg = 0; dg < 4; ++dg) oacc[st][dg] = (floatx4){0.f, 0.f, 0.f, 0.f};
  }

  short8 ones;
#pragma unroll
  for (int j = 0; j < 8; ++j) ones[j] = (short)0x3F80;  // bf16 1.0

  // global fragment base pointers (lane-fixed parts)
  const short* pK = QKV + (size_t)(b * SEQ + l16) * NQKV + 1024 + quad * 8;  // K[key=l16][d=quad*8..]
  const short* pV = Vtg + (size_t)(b * 64 + l16) * SEQ + quad * 8;           // V^T[d=l16][key=quad*8..]

  const int kbase = split * (SEQ / NSPLIT);

  for (int kk = kbase; kk < kbase + SEQ / NSPLIT; kk += 64) {
    // K A-frags: rows kg*16+l16 of the 64-key tile
    short8 kb[4][2];
#pragma unroll
    for (int kg = 0; kg < 4; ++kg) {
      const short* p = pK + (size_t)(kk + kg * 16) * NQKV;
      kb[kg][0] = *reinterpret_cast<const short8*>(p);
      kb[kg][1] = *reinterpret_cast<const short8*>(p + 32);
    }
    // V B-frags: V^T rows dg*16+l16, keys kk+quad*8 (+32)
    short8 vb[4][2];
#pragma unroll
    for (int dg = 0; dg < 4; ++dg) {
      const short* p = pV + (size_t)(dg * 16) * SEQ + kk;
      vb[dg][0] = *reinterpret_cast<const short8*>(p);
      vb[dg][1] = *reinterpret_cast<const short8*>(p + 32);
    }

#pragma unroll
    for (int st = 0; st < 2; ++st) {
      // S^T = K·Q^T ; p = exp2(s) ; pack (v_perm trunc) -> wave-private Ps
#pragma unroll
      for (int kg = 0; kg < 4; ++kg) {
        floatx4 s4 = (floatx4){0.f, 0.f, 0.f, 0.f};
        s4 = __builtin_amdgcn_mfma_f32_16x16x32_bf16(kb[kg][0], aq[st][0], s4, 0, 0, 0);
        s4 = __builtin_amdgcn_mfma_f32_16x16x32_bf16(kb[kg][1], aq[st][1], s4, 0, 0, 0);
        float p0 = __builtin_exp2f(s4[0]);
        float p1 = __builtin_exp2f(s4[1]);
        float p2 = __builtin_exp2f(s4[2]);
        float p3 = __builtin_exp2f(s4[3]);
        uint2 pk;
        pk.x = pack_trunc(p0, p1);
        pk.y = pack_trunc(p2, p3);
        *reinterpret_cast<uint2*>(&myPs[l16 * 72 + kg * 16 + quad * 4]) = pk;
      }
      // O += P·V ; l += P·ones  (same-wave in-order LDS: no barrier needed)
      short8 ap0 = *reinterpret_cast<const short8*>(&myPs[l16 * 72 + quad * 8]);
      short8 ap1 = *reinterpret_cast<const short8*>(&myPs[l16 * 72 + 32 + quad * 8]);
      lacc[st] = __builtin_amdgcn_mfma_f32_16x16x32_bf16(ap0, ones, lacc[st], 0, 0, 0);
      lacc[st] = __builtin_amdgcn_mfma_f32_16x16x32_bf16(ap1, ones, lacc[st], 0, 0, 0);
#pragma unroll
      for (int dg = 0; dg < 4; ++dg) {
        oacc[st][dg] = __builtin_amdgcn_mfma_f32_16x16x32_bf16(ap0, vb[dg][0], oacc[st][dg], 0, 0, 0);
        oacc[st][dg] = __builtin_amdgcn_mfma_f32_16x16x32_bf16(ap1, vb[dg][1], oacc[st][dg], 0, 0, 0);
      }
    }
  }

  // partial epilogue: fp16 O, fp32 l
#pragma unroll
  for (int st = 0; st < 2; ++st) {
#pragma unroll
    for (int rg = 0; rg < 4; ++rg) {
      const int qg = s0 + w * 32 + st * 16 + quad * 4 + rg;
      _Float16* dst = Opart + ((size_t)(split * 32 + bh) * SEQ + qg) * 64 + l16;
#pragma unroll
      for (int dg = 0; dg < 4; ++dg) dst[dg * 16] = (_Float16)oacc[st][dg][rg];
      if (l16 == 0) lpart[(size_t)(split * 32 + bh) * SEQ + qg] = lacc[st][rg];
    }
  }
}

// ---------------------------------------------------------------------------
// combine: Att[b*S+q][h*64+d] = (sum_s O_s)/(sum_s l_s), bf16 out
// ---------------------------------------------------------------------------
__global__ __launch_bounds__(256)
void combine_kernel(const _Float16* __restrict__ Opart, const float* __restrict__ lpart,
                    short* __restrict__ Att) {
  const int idx = blockIdx.x * 256 + threadIdx.x;   // 524288 total
  const int r   = idx >> 3;                          // bh*2048 + q
  const int d0  = (idx & 7) * 8;
  float l = 0.f;
  float o[8] = {0.f,0.f,0.f,0.f,0.f,0.f,0.f,0.f};
#pragma unroll
  for (int s = 0; s < NSPLIT; ++s) {
    const _Float16* op = Opart + ((size_t)(s * 32 * SEQ) + r) * 64 + d0;
    l += lpart[(size_t)s * 32 * SEQ + r];
#pragma unroll
    for (int j = 0; j < 8; ++j) o[j] += (float)op[j];
  }
  const float inv = 1.0f / l;
  short8 ov;
#pragma unroll
  for (int j = 0; j < 8; ++j) ov[j] = f2bf(o[j] * inv);
  const int bhh = r >> 11, q = r & 2047;
  const int bb = bhh >> 4, hh = bhh & 15;
  *reinterpret_cast<short8*>(&Att[(size_t)(bb * SEQ + q) * D_MODEL + hh * HD + d0]) = ov;
}

// ---------------------------------------------------------------------------
extern "C" void kernel_launch(void* const* d_in, const int* in_sizes, int n_in,
                              void* d_out, int out_size, void* d_ws, size_t ws_size,
                              hipStream_t stream) {
  const float* x  = (const float*)d_in[0];
  const float* Wq = (const float*)d_in[1];
  const float* bq = (const float*)d_in[2];
  const float* Wk = (const float*)d_in[3];
  const float* bk = (const float*)d_in[4];
  const float* Wv = (const float*)d_in[5];
  const float* bv = (const float*)d_in[6];
  const float* Wo = (const float*)d_in[7];
  const float* bo = (const float*)d_in[8];
  float* out = (float*)d_out;

  short* Wqkv_t = (short*)d_ws;                              // 1152*1024
  short* Wo_t   = Wqkv_t + (size_t)NQKV * D_MODEL;           // 1024*1024
  short* xb     = Wo_t + (size_t)D_MODEL * D_MODEL;          // 4096*1024
  short* QKV    = xb + (size_t)MROWS * D_MODEL;              // 4096*1152
  short* Att    = QKV + (size_t)MROWS * NQKV;                // 4096*1024
  short* Vtg    = Att + (size_t)MROWS * D_MODEL;             // 2*64*2048
  float* bqkv   = (float*)(Vtg + (size_t)BATCH * HD * SEQ);  // 1152
  float* lpart  = bqkv + 1152;                               // NSPLIT*32*2048
  _Float16* Opart = (_Float16*)(lpart + (size_t)NSPLIT * 32 * SEQ);  // NSPLIT*32*2048*64

  prep_kernel<<<2597, 256, 0, stream>>>(x, Wq, Wk, Wv, Wo, bq, bk, bv,
                                        xb, Wqkv_t, Wo_t, bqkv);

  // QKV projection; Q columns pre-scaled by 0.125*log2(e)
  gemm_mfma_bt<true, 1024><<<dim3(MROWS / 128, NQKV / 64), 256, 0, stream>>>(
      xb, Wqkv_t, bqkv, QKV, MROWS, NQKV, D_MODEL);

  vt_kernel<<<dim3(SEQ / 64, BATCH), 256, 0, stream>>>(QKV, Vtg);

  mqa_flash_bf16<<<dim3(SEQ / 128, BATCH * NHEADS, NSPLIT), 256, 0, stream>>>(
      QKV, Vtg, Opart, lpart);

  combine_kernel<<<2048, 256, 0, stream>>>(Opart, lpart, Att);

  gemm_mfma_bt<false, 0><<<dim3(MROWS / 128, D_MODEL / 64), 256, 0, stream>>>(
      Att, Wo_t, bo, out, MROWS, D_MODEL, D_MODEL);
}

// Round 8
// 185.452 us; speedup vs baseline: 2.5242x; 1.3373x over previous
//
#include <hip/hip_runtime.h>
#include <hip/hip_bf16.h>

#define D_MODEL 1024
#define NHEADS  16
#define HD      64
#define BATCH   2
#define SEQ     2048
#define MROWS   4096
#define NQKV    1152    // 1024 Q | 64 K | 64 V
#define NSPLIT  4

typedef short  short8  __attribute__((ext_vector_type(8)));
typedef float  floatx4 __attribute__((ext_vector_type(4)));

// fp32 -> bf16 (RNE)
__device__ inline short f2bf(float f) {
  unsigned u = __builtin_bit_cast(unsigned, f);
  u = (u + 0x7FFF + ((u >> 16) & 1)) >> 16;
  return (short)u;
}

// pack two f32 -> dword of two bf16 (truncation) in ONE v_perm_b32
__device__ inline unsigned pack_trunc(float lo, float hi) {
  return __builtin_amdgcn_perm(__builtin_bit_cast(unsigned, hi),
                               __builtin_bit_cast(unsigned, lo), 0x07060302u);
}

// async 16B global -> LDS (lds base wave-uniform; HW adds lane*16)
__device__ inline void async_copy16(const short* g, short* l) {
  __builtin_amdgcn_global_load_lds(
      (const __attribute__((address_space(1))) unsigned int*)g,
      (__attribute__((address_space(3))) unsigned int*)l, 16, 0, 0);
}

// ---------------------------------------------------------------------------
// Mega prep: weight transposes (bf16 B^T pack), bias pack, x -> bf16
// ---------------------------------------------------------------------------
__global__ __launch_bounds__(256)
void prep_kernel(const float* __restrict__ x,  const float* __restrict__ Wq,
                 const float* __restrict__ Wk, const float* __restrict__ Wv,
                 const float* __restrict__ Wo, const float* __restrict__ bq,
                 const float* __restrict__ bk, const float* __restrict__ bv,
                 short* __restrict__ xb, short* __restrict__ Wqkv_t,
                 short* __restrict__ Wo_t, float* __restrict__ bqkv) {
  const int id = blockIdx.x;
  const int t  = threadIdx.x;
  if (id < 544) {
    __shared__ short Ts[64 * 72];
    const float* src; short* dst; int N, off, tile;
    if (id < 256)      { src = Wq; dst = Wqkv_t; N = 1024; off = 0;    tile = id; }
    else if (id < 272) { src = Wk; dst = Wqkv_t; N = 64;   off = 1024; tile = id - 256; }
    else if (id < 288) { src = Wv; dst = Wqkv_t; N = 64;   off = 1088; tile = id - 272; }
    else               { src = Wo; dst = Wo_t;   N = 1024; off = 0;    tile = id - 288; }
    const int k0 = (N == 1024) ? (tile & 15) * 64 : tile * 64;
    const int n0 = (N == 1024) ? (tile >> 4) * 64 : 0;
    {
      const int r = t >> 2, c = (t & 3) * 16;
      const float* s = src + (size_t)(k0 + r) * N + n0 + c;
#pragma unroll
      for (int j = 0; j < 16; j += 4) {
        float4 v = *reinterpret_cast<const float4*>(s + j);
        Ts[r * 72 + c + j + 0] = f2bf(v.x); Ts[r * 72 + c + j + 1] = f2bf(v.y);
        Ts[r * 72 + c + j + 2] = f2bf(v.z); Ts[r * 72 + c + j + 3] = f2bf(v.w);
      }
    }
    __syncthreads();
    {
      const int n = t >> 2, kc = (t & 3) * 16;
      short8 o0, o1;
#pragma unroll
      for (int j = 0; j < 8; ++j) o0[j] = Ts[(kc + j) * 72 + n];
#pragma unroll
      for (int j = 0; j < 8; ++j) o1[j] = Ts[(kc + 8 + j) * 72 + n];
      short* d = dst + (size_t)(off + n0 + n) * 1024 + k0 + kc;
      *reinterpret_cast<short8*>(d)     = o0;
      *reinterpret_cast<short8*>(d + 8) = o1;
    }
  } else if (id < 549) {
    const int i = (id - 544) * 256 + t;
    if (i < 1024)      bqkv[i] = bq[i];
    else if (i < 1088) bqkv[i] = bk[i - 1024];
    else if (i < 1152) bqkv[i] = bv[i - 1088];
  } else {
    const int i = ((id - 549) * 256 + t) * 8;
    if (i < MROWS * D_MODEL) {
      float4 a = *reinterpret_cast<const float4*>(x + i);
      float4 b = *reinterpret_cast<const float4*>(x + i + 4);
      short8 o;
      o[0] = f2bf(a.x); o[1] = f2bf(a.y); o[2] = f2bf(a.z); o[3] = f2bf(a.w);
      o[4] = f2bf(b.x); o[5] = f2bf(b.y); o[6] = f2bf(b.z); o[7] = f2bf(b.w);
      *reinterpret_cast<short8*>(xb + i) = o;
    }
  }
}

// ---------------------------------------------------------------------------
// V^T pre-pass: QKV cols 1088..1151 -> Vtg[b][d][s]  ([2][64][2048] bf16)
// ---------------------------------------------------------------------------
__global__ __launch_bounds__(256)
void vt_kernel(const short* __restrict__ QKV, short* __restrict__ Vtg) {
  __shared__ short Ts[64 * 72];
  const int b = blockIdx.y, k0 = blockIdx.x * 64;
  const int t = threadIdx.x;
  {
    const int r = t >> 2, c = (t & 3) * 16;
    const short* s = &QKV[(size_t)(b * SEQ + k0 + r) * NQKV + 1088 + c];
    *reinterpret_cast<short8*>(&Ts[r * 72 + c])     = *reinterpret_cast<const short8*>(s);
    *reinterpret_cast<short8*>(&Ts[r * 72 + c + 8]) = *reinterpret_cast<const short8*>(s + 8);
  }
  __syncthreads();
  {
    const int d = t >> 2, kc = (t & 3) * 16;
    short8 o0, o1;
#pragma unroll
    for (int j = 0; j < 8; ++j) o0[j] = Ts[(kc + j) * 72 + d];
#pragma unroll
    for (int j = 0; j < 8; ++j) o1[j] = Ts[(kc + 8 + j) * 72 + d];
    short* dst = &Vtg[(size_t)(b * 64 + d) * SEQ + k0 + kc];
    *reinterpret_cast<short8*>(dst)     = o0;
    *reinterpret_cast<short8*>(dst + 8) = o1;
  }
}

// ---------------------------------------------------------------------------
// bf16 MFMA GEMM, 128x64 tile, BK=64.  C = A @ Bt^T + bias.
// SCALE_N: columns < SCALE_N scaled by 0.125*log2(e) (folds attention scale).
// ---------------------------------------------------------------------------
template<bool OUT_BF16, int SCALE_N>
__global__ __launch_bounds__(256)
void gemm_mfma_bt(const short* __restrict__ A, const short* __restrict__ Bt,
                  const float* __restrict__ bias, void* __restrict__ Cout,
                  int M, int N, int K) {
  __shared__ short As[128 * 64];   // 16 KB
  __shared__ short Bs[64 * 64];    // 8 KB
  const int t    = threadIdx.x;
  const int w    = t >> 6;
  const int lane = t & 63;
  const int quad = lane >> 4;
  const int l16  = lane & 15;
  const int bm   = blockIdx.x * 128;
  const int bn   = blockIdx.y * 64;
  const int wm   = (w >> 1) * 64;
  const int wn   = (w & 1) * 32;

  const int srow = t >> 3;
  const int cc   = ((t & 7) ^ (srow & 7)) * 8;
  const short* gA = A  + (size_t)(bm + srow) * K + cc;
  const short* gB = Bt + (size_t)(bn + srow) * K + cc;
  short* lA = As + t * 8;
  short* lB = Bs + t * 8;

  floatx4 acc[4][2];
#pragma unroll
  for (int i = 0; i < 4; ++i)
#pragma unroll
    for (int j = 0; j < 2; ++j) acc[i][j] = (floatx4){0.f, 0.f, 0.f, 0.f};

  const int xr = l16 & 7;

  for (int k0 = 0; k0 < K; k0 += 64) {
    __syncthreads();
    async_copy16(gA + k0, lA);
    async_copy16(gA + (size_t)32 * K + k0, lA + 2048);
    async_copy16(gA + (size_t)64 * K + k0, lA + 4096);
    async_copy16(gA + (size_t)96 * K + k0, lA + 6144);
    async_copy16(gB + k0, lB);
    async_copy16(gB + (size_t)32 * K + k0, lB + 2048);
    __syncthreads();

    short8 fa0[4], fa1[4], fb0[2], fb1[2];
#pragma unroll
    for (int mi = 0; mi < 4; ++mi) {
      const int row = wm + mi * 16 + l16;
      fa0[mi] = *reinterpret_cast<const short8*>(&As[row * 64 + (quad ^ xr) * 8]);
      fa1[mi] = *reinterpret_cast<const short8*>(&As[row * 64 + ((4 + quad) ^ xr) * 8]);
    }
#pragma unroll
    for (int ni = 0; ni < 2; ++ni) {
      const int row = wn + ni * 16 + l16;
      fb0[ni] = *reinterpret_cast<const short8*>(&Bs[row * 64 + (quad ^ xr) * 8]);
      fb1[ni] = *reinterpret_cast<const short8*>(&Bs[row * 64 + ((4 + quad) ^ xr) * 8]);
    }
#pragma unroll
    for (int mi = 0; mi < 4; ++mi)
#pragma unroll
      for (int ni = 0; ni < 2; ++ni) {
        acc[mi][ni] = __builtin_amdgcn_mfma_f32_16x16x32_bf16(fa0[mi], fb0[ni], acc[mi][ni], 0, 0, 0);
        acc[mi][ni] = __builtin_amdgcn_mfma_f32_16x16x32_bf16(fa1[mi], fb1[ni], acc[mi][ni], 0, 0, 0);
      }
  }

#pragma unroll
  for (int ni = 0; ni < 2; ++ni) {
    const int col = bn + wn + ni * 16 + l16;
    const float bs = bias[col];
    const float sc = (col < SCALE_N) ? 0.18033688f : 1.0f;  // 0.125*log2(e)
#pragma unroll
    for (int mi = 0; mi < 4; ++mi) {
      const int row = bm + wm + mi * 16 + quad * 4;
#pragma unroll
      for (int r = 0; r < 4; ++r) {
        const float v = (acc[mi][ni][r] + bs) * sc;
        if (OUT_BF16)
          ((short*)Cout)[(size_t)(row + r) * N + col] = f2bf(v);
        else
          ((float*)Cout)[(size_t)(row + r) * N + col] = v;
      }
    }
  }
}

// ---------------------------------------------------------------------------
// bf16 flash MQA (R5 DMA-staging structure + R7 numerics).
//  - K/V staged to LDS via global_load_lds, XOR-swizzled (conflict-lean)
//  - wave owns 32 q-rows as 2 sequential 16-row strips; 16-row wave-private Ps
//  - Q pre-scaled by 0.125*log2e in QKV GEMM -> p = exp2(s) directly
//  - KV-split=4 via grid.z; partials O fp16 / l fp32 (exact combine)
//  - LDS 25.6 KB -> 6 blocks/CU capacity; grid 2048 -> 8/CU offered
// ---------------------------------------------------------------------------
__global__ __launch_bounds__(256, 4)
void mqa_flash_bf16(const short* __restrict__ QKV, const short* __restrict__ Vtg,
                    _Float16* __restrict__ Opart, float* __restrict__ lpart) {
  const int bh    = blockIdx.y;
  const int b     = bh >> 4;
  const int h     = bh & 15;
  const int s0    = blockIdx.x * 128;
  const int split = blockIdx.z;
  const int t     = threadIdx.x;
  const int w     = t >> 6;
  const int lane  = t & 63;
  const int quad  = lane >> 4;
  const int l16   = lane & 15;

  __shared__ short KVs[8192];         // Ks [0,4096), Vt [4096,8192): 64 x 64
  __shared__ short Ps[4 * 16 * 72];   // wave-private 16-row P scratch
  short* Ks   = KVs;
  short* Vt   = KVs + 4096;
  short* myPs = Ps + w * 16 * 72;

  // Q B-frags (pre-scaled in GEMM epilogue)
  short8 aq[2][2];
#pragma unroll
  for (int st = 0; st < 2; ++st) {
    const short* qrow = &QKV[(size_t)(b * SEQ + s0 + w * 32 + st * 16 + l16) * NQKV + h * HD];
    aq[st][0] = *reinterpret_cast<const short8*>(qrow + quad * 8);
    aq[st][1] = *reinterpret_cast<const short8*>(qrow + 32 + quad * 8);
  }

  floatx4 oacc[2][4];
  floatx4 lacc[2];
#pragma unroll
  for (int st = 0; st < 2; ++st) {
    lacc[st] = (floatx4){0.f, 0.f, 0.f, 0.f};
#pragma unroll
    for (int dg = 0; dg < 4; ++dg) oacc[st][dg] = (floatx4){0.f, 0.f, 0.f, 0.f};
  }

  short8 ones;
#pragma unroll
  for (int j = 0; j < 8; ++j) ones[j] = (short)0x3F80;  // bf16 1.0

  // staging source (XOR-swizzled): slot s = t -> row s>>3, phys chunk s&7,
  // logical chunk (s&7)^(row&7)
  const int srow = t >> 3;                        // 0..31
  const int cc   = ((t & 7) ^ (srow & 7)) * 8;
  const short* gK0 = QKV + (size_t)(b * SEQ + srow) * NQKV + 1024 + cc;
  const short* gK1 = gK0 + (size_t)32 * NQKV;
  const short* gV0 = Vtg + (size_t)(b * 64 + srow) * SEQ + cc;
  const short* gV1 = gV0 + (size_t)32 * SEQ;
  short* lK0 = Ks + w * 512;
  short* lK1 = Ks + 2048 + w * 512;
  short* lV0 = Vt + w * 512;
  short* lV1 = Vt + 2048 + w * 512;

  const int xr = l16 & 7;
  const int kbase = split * (SEQ / NSPLIT);

  for (int kk = kbase; kk < kbase + SEQ / NSPLIT; kk += 64) {
    __syncthreads();   // prior frag reads of Ks/Vt complete
    async_copy16(gK0 + (size_t)kk * NQKV, lK0);
    async_copy16(gK1 + (size_t)kk * NQKV, lK1);
    async_copy16(gV0 + kk, lV0);
    async_copy16(gV1 + kk, lV1);
    __syncthreads();   // staging visible

    // K A-frags + V B-frags (shared across strips; XOR-swizzled reads)
    short8 kb[4][2], vb[4][2];
#pragma unroll
    for (int kg = 0; kg < 4; ++kg) {
      kb[kg][0] = *reinterpret_cast<const short8*>(&Ks[(kg * 16 + l16) * 64 + (quad ^ xr) * 8]);
      kb[kg][1] = *reinterpret_cast<const short8*>(&Ks[(kg * 16 + l16) * 64 + ((4 + quad) ^ xr) * 8]);
    }
#pragma unroll
    for (int dg = 0; dg < 4; ++dg) {
      vb[dg][0] = *reinterpret_cast<const short8*>(&Vt[(dg * 16 + l16) * 64 + (quad ^ xr) * 8]);
      vb[dg][1] = *reinterpret_cast<const short8*>(&Vt[(dg * 16 + l16) * 64 + ((4 + quad) ^ xr) * 8]);
    }

#pragma unroll
    for (int st = 0; st < 2; ++st) {
      // S^T = K·Q^T ; p = exp2(s) ; pack (v_perm trunc) -> wave-private Ps
#pragma unroll
      for (int kg = 0; kg < 4; ++kg) {
        floatx4 s4 = (floatx4){0.f, 0.f, 0.f, 0.f};
        s4 = __builtin_amdgcn_mfma_f32_16x16x32_bf16(kb[kg][0], aq[st][0], s4, 0, 0, 0);
        s4 = __builtin_amdgcn_mfma_f32_16x16x32_bf16(kb[kg][1], aq[st][1], s4, 0, 0, 0);
        float p0 = __builtin_exp2f(s4[0]);
        float p1 = __builtin_exp2f(s4[1]);
        float p2 = __builtin_exp2f(s4[2]);
        float p3 = __builtin_exp2f(s4[3]);
        uint2 pk;
        pk.x = pack_trunc(p0, p1);
        pk.y = pack_trunc(p2, p3);
        *reinterpret_cast<uint2*>(&myPs[l16 * 72 + kg * 16 + quad * 4]) = pk;
      }
      // O += P·V ; l += P·ones  (same-wave in-order LDS: no barrier)
      short8 ap0 = *reinterpret_cast<const short8*>(&myPs[l16 * 72 + quad * 8]);
      short8 ap1 = *reinterpret_cast<const short8*>(&myPs[l16 * 72 + 32 + quad * 8]);
      lacc[st] = __builtin_amdgcn_mfma_f32_16x16x32_bf16(ap0, ones, lacc[st], 0, 0, 0);
      lacc[st] = __builtin_amdgcn_mfma_f32_16x16x32_bf16(ap1, ones, lacc[st], 0, 0, 0);
#pragma unroll
      for (int dg = 0; dg < 4; ++dg) {
        oacc[st][dg] = __builtin_amdgcn_mfma_f32_16x16x32_bf16(ap0, vb[dg][0], oacc[st][dg], 0, 0, 0);
        oacc[st][dg] = __builtin_amdgcn_mfma_f32_16x16x32_bf16(ap1, vb[dg][1], oacc[st][dg], 0, 0, 0);
      }
    }
  }

  // partial epilogue: fp16 O, fp32 l
#pragma unroll
  for (int st = 0; st < 2; ++st) {
#pragma unroll
    for (int rg = 0; rg < 4; ++rg) {
      const int qg = s0 + w * 32 + st * 16 + quad * 4 + rg;
      _Float16* dst = Opart + ((size_t)(split * 32 + bh) * SEQ + qg) * 64 + l16;
#pragma unroll
      for (int dg = 0; dg < 4; ++dg) dst[dg * 16] = (_Float16)oacc[st][dg][rg];
      if (l16 == 0) lpart[(size_t)(split * 32 + bh) * SEQ + qg] = lacc[st][rg];
    }
  }
}

// ---------------------------------------------------------------------------
// combine: Att[b*S+q][h*64+d] = (sum_s O_s)/(sum_s l_s), bf16 out
// ---------------------------------------------------------------------------
__global__ __launch_bounds__(256)
void combine_kernel(const _Float16* __restrict__ Opart, const float* __restrict__ lpart,
                    short* __restrict__ Att) {
  const int idx = blockIdx.x * 256 + threadIdx.x;   // 524288 total
  const int r   = idx >> 3;                          // bh*2048 + q
  const int d0  = (idx & 7) * 8;
  float l = 0.f;
  float o[8] = {0.f,0.f,0.f,0.f,0.f,0.f,0.f,0.f};
#pragma unroll
  for (int s = 0; s < NSPLIT; ++s) {
    const _Float16* op = Opart + ((size_t)(s * 32 * SEQ) + r) * 64 + d0;
    l += lpart[(size_t)s * 32 * SEQ + r];
#pragma unroll
    for (int j = 0; j < 8; ++j) o[j] += (float)op[j];
  }
  const float inv = 1.0f / l;
  short8 ov;
#pragma unroll
  for (int j = 0; j < 8; ++j) ov[j] = f2bf(o[j] * inv);
  const int bhh = r >> 11, q = r & 2047;
  const int bb = bhh >> 4, hh = bhh & 15;
  *reinterpret_cast<short8*>(&Att[(size_t)(bb * SEQ + q) * D_MODEL + hh * HD + d0]) = ov;
}

// ---------------------------------------------------------------------------
extern "C" void kernel_launch(void* const* d_in, const int* in_sizes, int n_in,
                              void* d_out, int out_size, void* d_ws, size_t ws_size,
                              hipStream_t stream) {
  const float* x  = (const float*)d_in[0];
  const float* Wq = (const float*)d_in[1];
  const float* bq = (const float*)d_in[2];
  const float* Wk = (const float*)d_in[3];
  const float* bk = (const float*)d_in[4];
  const float* Wv = (const float*)d_in[5];
  const float* bv = (const float*)d_in[6];
  const float* Wo = (const float*)d_in[7];
  const float* bo = (const float*)d_in[8];
  float* out = (float*)d_out;

  short* Wqkv_t = (short*)d_ws;                              // 1152*1024
  short* Wo_t   = Wqkv_t + (size_t)NQKV * D_MODEL;           // 1024*1024
  short* xb     = Wo_t + (size_t)D_MODEL * D_MODEL;          // 4096*1024
  short* QKV    = xb + (size_t)MROWS * D_MODEL;              // 4096*1152
  short* Att    = QKV + (size_t)MROWS * NQKV;                // 4096*1024
  short* Vtg    = Att + (size_t)MROWS * D_MODEL;             // 2*64*2048
  float* bqkv   = (float*)(Vtg + (size_t)BATCH * HD * SEQ);  // 1152
  float* lpart  = bqkv + 1152;                               // NSPLIT*32*2048
  _Float16* Opart = (_Float16*)(lpart + (size_t)NSPLIT * 32 * SEQ);  // NSPLIT*32*2048*64

  prep_kernel<<<2597, 256, 0, stream>>>(x, Wq, Wk, Wv, Wo, bq, bk, bv,
                                        xb, Wqkv_t, Wo_t, bqkv);

  // QKV projection; Q columns pre-scaled by 0.125*log2(e)
  gemm_mfma_bt<true, 1024><<<dim3(MROWS / 128, NQKV / 64), 256, 0, stream>>>(
      xb, Wqkv_t, bqkv, QKV, MROWS, NQKV, D_MODEL);

  vt_kernel<<<dim3(SEQ / 64, BATCH), 256, 0, stream>>>(QKV, Vtg);

  mqa_flash_bf16<<<dim3(SEQ / 128, BATCH * NHEADS, NSPLIT), 256, 0, stream>>>(
      QKV, Vtg, Opart, lpart);

  combine_kernel<<<2048, 256, 0, stream>>>(Opart, lpart, Att);

  gemm_mfma_bt<false, 0><<<dim3(MROWS / 128, D_MODEL / 64), 256, 0, stream>>>(
      Att, Wo_t, bo, out, MROWS, D_MODEL, D_MODEL);
}

// Round 9
// 181.129 us; speedup vs baseline: 2.5845x; 1.0239x over previous
//
#include <hip/hip_runtime.h>
#include <hip/hip_bf16.h>

#define D_MODEL 1024
#define NHEADS  16
#define HD      64
#define BATCH   2
#define SEQ     2048
#define MROWS   4096
#define NQKV    1152    // 1024 Q | 64 K | 64 V
#define NSPLIT  2

typedef short  short4v __attribute__((ext_vector_type(4)));
typedef short  short8  __attribute__((ext_vector_type(8)));
typedef float  floatx4 __attribute__((ext_vector_type(4)));

// fp32 -> bf16 (RNE)
__device__ inline short f2bf(float f) {
  unsigned u = __builtin_bit_cast(unsigned, f);
  u = (u + 0x7FFF + ((u >> 16) & 1)) >> 16;
  return (short)u;
}

// pack two f32 -> dword of two bf16 (truncation) in ONE v_perm_b32
__device__ inline unsigned pack_trunc(float lo, float hi) {
  return __builtin_amdgcn_perm(__builtin_bit_cast(unsigned, hi),
                               __builtin_bit_cast(unsigned, lo), 0x07060302u);
}

// async 16B global -> LDS (lds base wave-uniform; HW adds lane*16)
__device__ inline void async_copy16(const short* g, short* l) {
  __builtin_amdgcn_global_load_lds(
      (const __attribute__((address_space(1))) unsigned int*)g,
      (__attribute__((address_space(3))) unsigned int*)l, 16, 0, 0);
}

// ---------------------------------------------------------------------------
// Mega prep: weight transposes (bf16 B^T pack), bias pack, x -> bf16
// ---------------------------------------------------------------------------
__global__ __launch_bounds__(256)
void prep_kernel(const float* __restrict__ x,  const float* __restrict__ Wq,
                 const float* __restrict__ Wk, const float* __restrict__ Wv,
                 const float* __restrict__ Wo, const float* __restrict__ bq,
                 const float* __restrict__ bk, const float* __restrict__ bv,
                 short* __restrict__ xb, short* __restrict__ Wqkv_t,
                 short* __restrict__ Wo_t, float* __restrict__ bqkv) {
  const int id = blockIdx.x;
  const int t  = threadIdx.x;
  if (id < 544) {
    __shared__ short Ts[64 * 72];
    const float* src; short* dst; int N, off, tile;
    if (id < 256)      { src = Wq; dst = Wqkv_t; N = 1024; off = 0;    tile = id; }
    else if (id < 272) { src = Wk; dst = Wqkv_t; N = 64;   off = 1024; tile = id - 256; }
    else if (id < 288) { src = Wv; dst = Wqkv_t; N = 64;   off = 1088; tile = id - 272; }
    else               { src = Wo; dst = Wo_t;   N = 1024; off = 0;    tile = id - 288; }
    const int k0 = (N == 1024) ? (tile & 15) * 64 : tile * 64;
    const int n0 = (N == 1024) ? (tile >> 4) * 64 : 0;
    {
      const int r = t >> 2, c = (t & 3) * 16;
      const float* s = src + (size_t)(k0 + r) * N + n0 + c;
#pragma unroll
      for (int j = 0; j < 16; j += 4) {
        float4 v = *reinterpret_cast<const float4*>(s + j);
        Ts[r * 72 + c + j + 0] = f2bf(v.x); Ts[r * 72 + c + j + 1] = f2bf(v.y);
        Ts[r * 72 + c + j + 2] = f2bf(v.z); Ts[r * 72 + c + j + 3] = f2bf(v.w);
      }
    }
    __syncthreads();
    {
      const int n = t >> 2, kc = (t & 3) * 16;
      short8 o0, o1;
#pragma unroll
      for (int j = 0; j < 8; ++j) o0[j] = Ts[(kc + j) * 72 + n];
#pragma unroll
      for (int j = 0; j < 8; ++j) o1[j] = Ts[(kc + 8 + j) * 72 + n];
      short* d = dst + (size_t)(off + n0 + n) * 1024 + k0 + kc;
      *reinterpret_cast<short8*>(d)     = o0;
      *reinterpret_cast<short8*>(d + 8) = o1;
    }
  } else if (id < 549) {
    const int i = (id - 544) * 256 + t;
    if (i < 1024)      bqkv[i] = bq[i];
    else if (i < 1088) bqkv[i] = bk[i - 1024];
    else if (i < 1152) bqkv[i] = bv[i - 1088];
  } else {
    const int i = ((id - 549) * 256 + t) * 8;
    if (i < MROWS * D_MODEL) {
      float4 a = *reinterpret_cast<const float4*>(x + i);
      float4 b = *reinterpret_cast<const float4*>(x + i + 4);
      short8 o;
      o[0] = f2bf(a.x); o[1] = f2bf(a.y); o[2] = f2bf(a.z); o[3] = f2bf(a.w);
      o[4] = f2bf(b.x); o[5] = f2bf(b.y); o[6] = f2bf(b.z); o[7] = f2bf(b.w);
      *reinterpret_cast<short8*>(xb + i) = o;
    }
  }
}

// ---------------------------------------------------------------------------
// bf16 MFMA GEMM, 128x64 tile, BK=64.  C = A @ Bt^T + bias.
// SCALE_N: cols < SCALE_N scaled by 0.125*log2(e) (folds attention scale).
// VT_FUSE: cols in [1088,1152) additionally written transposed to Vtg
//          ([2][64][2048] bf16) — replaces the standalone vt kernel.
// ---------------------------------------------------------------------------
template<bool OUT_BF16, int SCALE_N, bool VT_FUSE>
__global__ __launch_bounds__(256)
void gemm_mfma_bt(const short* __restrict__ A, const short* __restrict__ Bt,
                  const float* __restrict__ bias, void* __restrict__ Cout,
                  short* __restrict__ Vtg, int M, int N, int K) {
  __shared__ short As[128 * 64];   // 16 KB
  __shared__ short Bs[64 * 64];    // 8 KB
  const int t    = threadIdx.x;
  const int w    = t >> 6;
  const int lane = t & 63;
  const int quad = lane >> 4;
  const int l16  = lane & 15;
  const int bm   = blockIdx.x * 128;
  const int bn   = blockIdx.y * 64;
  const int wm   = (w >> 1) * 64;
  const int wn   = (w & 1) * 32;

  const int srow = t >> 3;
  const int cc   = ((t & 7) ^ (srow & 7)) * 8;
  const short* gA = A  + (size_t)(bm + srow) * K + cc;
  const short* gB = Bt + (size_t)(bn + srow) * K + cc;
  short* lA = As + t * 8;
  short* lB = Bs + t * 8;

  floatx4 acc[4][2];
#pragma unroll
  for (int i = 0; i < 4; ++i)
#pragma unroll
    for (int j = 0; j < 2; ++j) acc[i][j] = (floatx4){0.f, 0.f, 0.f, 0.f};

  const int xr = l16 & 7;

  for (int k0 = 0; k0 < K; k0 += 64) {
    __syncthreads();
    async_copy16(gA + k0, lA);
    async_copy16(gA + (size_t)32 * K + k0, lA + 2048);
    async_copy16(gA + (size_t)64 * K + k0, lA + 4096);
    async_copy16(gA + (size_t)96 * K + k0, lA + 6144);
    async_copy16(gB + k0, lB);
    async_copy16(gB + (size_t)32 * K + k0, lB + 2048);
    __syncthreads();

    short8 fa0[4], fa1[4], fb0[2], fb1[2];
#pragma unroll
    for (int mi = 0; mi < 4; ++mi) {
      const int row = wm + mi * 16 + l16;
      fa0[mi] = *reinterpret_cast<const short8*>(&As[row * 64 + (quad ^ xr) * 8]);
      fa1[mi] = *reinterpret_cast<const short8*>(&As[row * 64 + ((4 + quad) ^ xr) * 8]);
    }
#pragma unroll
    for (int ni = 0; ni < 2; ++ni) {
      const int row = wn + ni * 16 + l16;
      fb0[ni] = *reinterpret_cast<const short8*>(&Bs[row * 64 + (quad ^ xr) * 8]);
      fb1[ni] = *reinterpret_cast<const short8*>(&Bs[row * 64 + ((4 + quad) ^ xr) * 8]);
    }
#pragma unroll
    for (int mi = 0; mi < 4; ++mi)
#pragma unroll
      for (int ni = 0; ni < 2; ++ni) {
        acc[mi][ni] = __builtin_amdgcn_mfma_f32_16x16x32_bf16(fa0[mi], fb0[ni], acc[mi][ni], 0, 0, 0);
        acc[mi][ni] = __builtin_amdgcn_mfma_f32_16x16x32_bf16(fa1[mi], fb1[ni], acc[mi][ni], 0, 0, 0);
      }
  }

#pragma unroll
  for (int ni = 0; ni < 2; ++ni) {
    const int col = bn + wn + ni * 16 + l16;
    const float bs = bias[col];
    const float sc = (col < SCALE_N) ? 0.18033688f : 1.0f;  // 0.125*log2(e)
#pragma unroll
    for (int mi = 0; mi < 4; ++mi) {
      const int row = bm + wm + mi * 16 + quad * 4;
      short4v vt4;
#pragma unroll
      for (int r = 0; r < 4; ++r) {
        const float v = (acc[mi][ni][r] + bs) * sc;
        if (OUT_BF16) {
          const short bv16 = f2bf(v);
          ((short*)Cout)[(size_t)(row + r) * N + col] = bv16;
          if (VT_FUSE) vt4[r] = bv16;
        } else {
          ((float*)Cout)[(size_t)(row + r) * N + col] = v;
        }
      }
      if (VT_FUSE && col >= 1088) {
        const int d = col - 1088;
        const int b = row >> 11, s = row & 2047;
        *reinterpret_cast<short4v*>(&Vtg[(size_t)(b * 64 + d) * SEQ + s]) = vt4;
      }
    }
  }
}

// ---------------------------------------------------------------------------
// bf16 flash MQA (DMA-staged, 128 keys per barrier pair).
//  - K/V staged to LDS via global_load_lds, XOR-swizzled; TWO 64-key tiles
//    per __syncthreads pair (half the sync/drain cost of R8)
//  - wave owns 32 q-rows as 2 sequential 16-row strips; 16-row wave-private Ps
//  - Q pre-scaled by 0.125*log2e in QKV GEMM -> p = exp2(s) directly
//  - KV-split=2 via grid.z; partials O fp16 / l fp32 (exact combine)
// ---------------------------------------------------------------------------
__global__ __launch_bounds__(256, 3)
void mqa_flash_bf16(const short* __restrict__ QKV, const short* __restrict__ Vtg,
                    _Float16* __restrict__ Opart, float* __restrict__ lpart) {
  const int bh    = blockIdx.y;
  const int b     = bh >> 4;
  const int h     = bh & 15;
  const int s0    = blockIdx.x * 128;
  const int split = blockIdx.z;
  const int t     = threadIdx.x;
  const int w     = t >> 6;
  const int lane  = t & 63;
  const int quad  = lane >> 4;
  const int l16   = lane & 15;

  __shared__ short KVs[16384];        // K0|K1 [0,8192), V0|V1 [8192,16384)
  __shared__ short Ps[4 * 16 * 72];   // wave-private 16-row P scratch
  short* myPs = Ps + w * 16 * 72;

  // Q B-frags (pre-scaled in GEMM epilogue)
  short8 aq[2][2];
#pragma unroll
  for (int st = 0; st < 2; ++st) {
    const short* qrow = &QKV[(size_t)(b * SEQ + s0 + w * 32 + st * 16 + l16) * NQKV + h * HD];
    aq[st][0] = *reinterpret_cast<const short8*>(qrow + quad * 8);
    aq[st][1] = *reinterpret_cast<const short8*>(qrow + 32 + quad * 8);
  }

  floatx4 oacc[2][4];
  floatx4 lacc[2];
#pragma unroll
  for (int st = 0; st < 2; ++st) {
    lacc[st] = (floatx4){0.f, 0.f, 0.f, 0.f};
#pragma unroll
    for (int dg = 0; dg < 4; ++dg) oacc[st][dg] = (floatx4){0.f, 0.f, 0.f, 0.f};
  }

  short8 ones;
#pragma unroll
  for (int j = 0; j < 8; ++j) ones[j] = (short)0x3F80;  // bf16 1.0

  // staging source (XOR-swizzled): slot s = t -> row s>>3, phys chunk s&7,
  // logical chunk (s&7)^(row&7)
  const int srow = t >> 3;                        // 0..31
  const int cc   = ((t & 7) ^ (srow & 7)) * 8;
  const short* gK0 = QKV + (size_t)(b * SEQ + srow) * NQKV + 1024 + cc;
  const short* gK1 = gK0 + (size_t)32 * NQKV;
  const short* gV0 = Vtg + (size_t)(b * 64 + srow) * SEQ + cc;
  const short* gV1 = gV0 + (size_t)32 * SEQ;
  short* lK0 = KVs + w * 512;          // tile half 0
  short* lK1 = KVs + 2048 + w * 512;
  short* lV0 = KVs + 8192 + w * 512;
  short* lV1 = KVs + 10240 + w * 512;

  const int xr = l16 & 7;
  const int kbase = split * (SEQ / NSPLIT);

  for (int kk = kbase; kk < kbase + SEQ / NSPLIT; kk += 128) {
    __syncthreads();   // prior frag reads of KVs complete
    // stage 128 keys (two 64-key tiles) of K and V^T
    async_copy16(gK0 + (size_t)kk * NQKV, lK0);
    async_copy16(gK1 + (size_t)kk * NQKV, lK1);
    async_copy16(gK0 + (size_t)(kk + 64) * NQKV, lK0 + 4096);
    async_copy16(gK1 + (size_t)(kk + 64) * NQKV, lK1 + 4096);
    async_copy16(gV0 + kk, lV0);
    async_copy16(gV1 + kk, lV1);
    async_copy16(gV0 + kk + 64, lV0 + 4096);
    async_copy16(gV1 + kk + 64, lV1 + 4096);
    __syncthreads();   // staging visible

#pragma unroll
    for (int half = 0; half < 2; ++half) {
      const short* Ks = KVs + half * 4096;
      const short* Vt = KVs + 8192 + half * 4096;

      // K A-frags + V B-frags (shared across strips; XOR-swizzled reads)
      short8 kb[4][2], vb[4][2];
#pragma unroll
      for (int kg = 0; kg < 4; ++kg) {
        kb[kg][0] = *reinterpret_cast<const short8*>(&Ks[(kg * 16 + l16) * 64 + (quad ^ xr) * 8]);
        kb[kg][1] = *reinterpret_cast<const short8*>(&Ks[(kg * 16 + l16) * 64 + ((4 + quad) ^ xr) * 8]);
      }
#pragma unroll
      for (int dg = 0; dg < 4; ++dg) {
        vb[dg][0] = *reinterpret_cast<const short8*>(&Vt[(dg * 16 + l16) * 64 + (quad ^ xr) * 8]);
        vb[dg][1] = *reinterpret_cast<const short8*>(&Vt[(dg * 16 + l16) * 64 + ((4 + quad) ^ xr) * 8]);
      }

#pragma unroll
      for (int st = 0; st < 2; ++st) {
        // S^T = K·Q^T ; p = exp2(s) ; pack (v_perm trunc) -> wave-private Ps
#pragma unroll
        for (int kg = 0; kg < 4; ++kg) {
          floatx4 s4 = (floatx4){0.f, 0.f, 0.f, 0.f};
          s4 = __builtin_amdgcn_mfma_f32_16x16x32_bf16(kb[kg][0], aq[st][0], s4, 0, 0, 0);
          s4 = __builtin_amdgcn_mfma_f32_16x16x32_bf16(kb[kg][1], aq[st][1], s4, 0, 0, 0);
          float p0 = __builtin_exp2f(s4[0]);
          float p1 = __builtin_exp2f(s4[1]);
          float p2 = __builtin_exp2f(s4[2]);
          float p3 = __builtin_exp2f(s4[3]);
          uint2 pk;
          pk.x = pack_trunc(p0, p1);
          pk.y = pack_trunc(p2, p3);
          *reinterpret_cast<uint2*>(&myPs[l16 * 72 + kg * 16 + quad * 4]) = pk;
        }
        // O += P·V ; l += P·ones  (same-wave in-order LDS: no barrier)
        short8 ap0 = *reinterpret_cast<const short8*>(&myPs[l16 * 72 + quad * 8]);
        short8 ap1 = *reinterpret_cast<const short8*>(&myPs[l16 * 72 + 32 + quad * 8]);
        lacc[st] = __builtin_amdgcn_mfma_f32_16x16x32_bf16(ap0, ones, lacc[st], 0, 0, 0);
        lacc[st] = __builtin_amdgcn_mfma_f32_16x16x32_bf16(ap1, ones, lacc[st], 0, 0, 0);
#pragma unroll
        for (int dg = 0; dg < 4; ++dg) {
          oacc[st][dg] = __builtin_amdgcn_mfma_f32_16x16x32_bf16(ap0, vb[dg][0], oacc[st][dg], 0, 0, 0);
          oacc[st][dg] = __builtin_amdgcn_mfma_f32_16x16x32_bf16(ap1, vb[dg][1], oacc[st][dg], 0, 0, 0);
        }
      }
    }
  }

  // partial epilogue: fp16 O, fp32 l
#pragma unroll
  for (int st = 0; st < 2; ++st) {
#pragma unroll
    for (int rg = 0; rg < 4; ++rg) {
      const int qg = s0 + w * 32 + st * 16 + quad * 4 + rg;
      _Float16* dst = Opart + ((size_t)(split * 32 + bh) * SEQ + qg) * 64 + l16;
#pragma unroll
      for (int dg = 0; dg < 4; ++dg) dst[dg * 16] = (_Float16)oacc[st][dg][rg];
      if (l16 == 0) lpart[(size_t)(split * 32 + bh) * SEQ + qg] = lacc[st][rg];
    }
  }
}

// ---------------------------------------------------------------------------
// combine: Att[b*S+q][h*64+d] = (sum_s O_s)/(sum_s l_s), bf16 out
// ---------------------------------------------------------------------------
__global__ __launch_bounds__(256)
void combine_kernel(const _Float16* __restrict__ Opart, const float* __restrict__ lpart,
                    short* __restrict__ Att) {
  const int idx = blockIdx.x * 256 + threadIdx.x;   // 524288 total
  const int r   = idx >> 3;                          // bh*2048 + q
  const int d0  = (idx & 7) * 8;
  float l = 0.f;
  float o[8] = {0.f,0.f,0.f,0.f,0.f,0.f,0.f,0.f};
#pragma unroll
  for (int s = 0; s < NSPLIT; ++s) {
    const _Float16* op = Opart + ((size_t)(s * 32 * SEQ) + r) * 64 + d0;
    l += lpart[(size_t)s * 32 * SEQ + r];
#pragma unroll
    for (int j = 0; j < 8; ++j) o[j] += (float)op[j];
  }
  const float inv = 1.0f / l;
  short8 ov;
#pragma unroll
  for (int j = 0; j < 8; ++j) ov[j] = f2bf(o[j] * inv);
  const int bhh = r >> 11, q = r & 2047;
  const int bb = bhh >> 4, hh = bhh & 15;
  *reinterpret_cast<short8*>(&Att[(size_t)(bb * SEQ + q) * D_MODEL + hh * HD + d0]) = ov;
}

// ---------------------------------------------------------------------------
extern "C" void kernel_launch(void* const* d_in, const int* in_sizes, int n_in,
                              void* d_out, int out_size, void* d_ws, size_t ws_size,
                              hipStream_t stream) {
  const float* x  = (const float*)d_in[0];
  const float* Wq = (const float*)d_in[1];
  const float* bq = (const float*)d_in[2];
  const float* Wk = (const float*)d_in[3];
  const float* bk = (const float*)d_in[4];
  const float* Wv = (const float*)d_in[5];
  const float* bv = (const float*)d_in[6];
  const float* Wo = (const float*)d_in[7];
  const float* bo = (const float*)d_in[8];
  float* out = (float*)d_out;

  short* Wqkv_t = (short*)d_ws;                              // 1152*1024
  short* Wo_t   = Wqkv_t + (size_t)NQKV * D_MODEL;           // 1024*1024
  short* xb     = Wo_t + (size_t)D_MODEL * D_MODEL;          // 4096*1024
  short* QKV    = xb + (size_t)MROWS * D_MODEL;              // 4096*1152
  short* Att    = QKV + (size_t)MROWS * NQKV;                // 4096*1024
  short* Vtg    = Att + (size_t)MROWS * D_MODEL;             // 2*64*2048
  float* bqkv   = (float*)(Vtg + (size_t)BATCH * HD * SEQ);  // 1152
  float* lpart  = bqkv + 1152;                               // NSPLIT*32*2048
  _Float16* Opart = (_Float16*)(lpart + (size_t)NSPLIT * 32 * SEQ);  // NSPLIT*32*2048*64

  prep_kernel<<<2597, 256, 0, stream>>>(x, Wq, Wk, Wv, Wo, bq, bk, bv,
                                        xb, Wqkv_t, Wo_t, bqkv);

  // QKV projection; Q cols pre-scaled; V cols also written transposed (Vtg)
  gemm_mfma_bt<true, 1024, true><<<dim3(MROWS / 128, NQKV / 64), 256, 0, stream>>>(
      xb, Wqkv_t, bqkv, QKV, Vtg, MROWS, NQKV, D_MODEL);

  mqa_flash_bf16<<<dim3(SEQ / 128, BATCH * NHEADS, NSPLIT), 256, 0, stream>>>(
      QKV, Vtg, Opart, lpart);

  combine_kernel<<<2048, 256, 0, stream>>>(Opart, lpart, Att);

  gemm_mfma_bt<false, 0, false><<<dim3(MROWS / 128, D_MODEL / 64), 256, 0, stream>>>(
      Att, Wo_t, bo, out, nullptr, MROWS, D_MODEL, D_MODEL);
}